// Round 5
// baseline (7273.530 us; speedup 1.0000x reference)
//
#include <hip/hip_runtime.h>
#include <math.h>

typedef __attribute__((ext_vector_type(8))) short short8;
typedef __attribute__((ext_vector_type(4))) float f32x4;
typedef unsigned int uint;
typedef unsigned short ushort;

// Problem constants
#define Lsteps 5
#define Hn 256
#define Wn 256
#define HWn 65536           // 256*256
#define BHW 524288          // 8*65536

// d_out float offsets
#define OUT_IMG    0
#define OUT_FIELDS 524288
#define OUT_RES    5767168
#define OUT_GRADS  8912896

// workspace float offsets
#define WS_IMG   0           // 524288
#define WS_PHIA  524288      // 5242880  [5][8][256][256][2]
#define WS_PHIB  5767168     // 5242880
#define WS_VTMP  11010048    // 1048576  [8][2][256][256]
#define WS_W2H   12058624    // 368640 f (737280 ushort)  [5][9][128 oc][128 ic] bf16
#define WS_W3P2  12427264    // 4680 f  [5][100 oc][9 tap] fp32 (reserve 5120)
#define WS_X2P   12432384    // 6815744 f = 13631488 ushort  [104 oc][2 bb][256][256] bf16

__device__ inline float lrelu(float s) { return s > 0.f ? s : 0.01f * s; }

__device__ inline ushort bf16r(float f) {
  uint u = __float_as_uint(f);
  return (ushort)((u + 0x7fffu + ((u >> 16) & 1u)) >> 16);
}
__device__ inline float bf2f(ushort h) { return __uint_as_float(((uint)h) << 16); }

__device__ inline void make_gauss(float* G) {
  float s = 0.f;
#pragma unroll
  for (int t = 0; t < 15; t++) {
    float d = (float)t - 7.f;
    G[t] = expf(-d * d * (1.f / 32.f));
    s += G[t];
  }
  float inv = 1.f / s;
#pragma unroll
  for (int t = 0; t < 15; t++) G[t] *= inv;
}

__device__ inline float bilin1(const float* __restrict__ p, float x, float y) {
  float x0f = floorf(x), y0f = floorf(y);
  int x0 = (int)x0f, y0 = (int)y0f;
  float fx = x - x0f, fy = y - y0f;
  float w00 = (1.f - fx) * (1.f - fy), w10 = fx * (1.f - fy);
  float w01 = (1.f - fx) * fy, w11 = fx * fy;
  float acc = 0.f;
  if ((unsigned)x0 < 256u && (unsigned)y0 < 256u) acc += w00 * p[y0 * 256 + x0];
  if ((unsigned)(x0 + 1) < 256u && (unsigned)y0 < 256u) acc += w10 * p[y0 * 256 + x0 + 1];
  if ((unsigned)x0 < 256u && (unsigned)(y0 + 1) < 256u) acc += w01 * p[(y0 + 1) * 256 + x0];
  if ((unsigned)(x0 + 1) < 256u && (unsigned)(y0 + 1) < 256u) acc += w11 * p[(y0 + 1) * 256 + x0 + 1];
  return acc;
}

__device__ inline void bilin2(const float* __restrict__ p, float x, float y,
                              float& o0, float& o1) {
  float x0f = floorf(x), y0f = floorf(y);
  int x0 = (int)x0f, y0 = (int)y0f;
  float fx = x - x0f, fy = y - y0f;
  float w00 = (1.f - fx) * (1.f - fy), w10 = fx * (1.f - fy);
  float w01 = (1.f - fx) * fy, w11 = fx * fy;
  o0 = 0.f; o1 = 0.f;
  if ((unsigned)x0 < 256u && (unsigned)y0 < 256u) {
    const float* q = p + (y0 * 256 + x0) * 2; o0 += w00 * q[0]; o1 += w00 * q[1];
  }
  if ((unsigned)(x0 + 1) < 256u && (unsigned)y0 < 256u) {
    const float* q = p + (y0 * 256 + x0 + 1) * 2; o0 += w10 * q[0]; o1 += w10 * q[1];
  }
  if ((unsigned)x0 < 256u && (unsigned)(y0 + 1) < 256u) {
    const float* q = p + ((y0 + 1) * 256 + x0) * 2; o0 += w01 * q[0]; o1 += w01 * q[1];
  }
  if ((unsigned)(x0 + 1) < 256u && (unsigned)(y0 + 1) < 256u) {
    const float* q = p + ((y0 + 1) * 256 + x0 + 1) * 2; o0 += w11 * q[0]; o1 += w11 * q[1];
  }
}

__global__ void init_res0_kernel(const float* __restrict__ z0, float* __restrict__ res0) {
  int idx = blockIdx.x * 256 + threadIdx.x;
  res0[idx] = z0[idx & 65535];
}

// w2 bf16: [l][tap][oc][ic], oc/ic zero-padded to 128
__global__ void w2p_prep(const float* __restrict__ w2, ushort* __restrict__ w2h) {
  int idx = blockIdx.x * 256 + threadIdx.x;     // 737280
  int l = idx / 147456;
  int r = idx - l * 147456;
  int tap = r >> 14;
  int r2 = r & 16383;
  int oc = r2 >> 7;
  int ic = r2 & 127;
  float v = (oc < 100 && ic < 100) ? w2[l * 90000 + oc * 900 + ic * 9 + tap] : 0.f;
  w2h[idx] = bf16r(v);
}

// w3p2[l][oc][tap] fp32, oc<100
__global__ void w3p2_prep(const float* __restrict__ w3, float* __restrict__ w3p2) {
  int idx = blockIdx.x * 256 + threadIdx.x;     // 4680
  if (idx >= Lsteps * 900) return;
  w3p2[idx] = w3[idx];   // same [l][oc][tap] order as input
}

__global__ void sobel_kernel(const float* __restrict__ img, float* __restrict__ gout) {
  int idx = blockIdx.x * 256 + threadIdx.x;
  int b = idx >> 16; int y = (idx >> 8) & 255; int x = idx & 255;
  const float* p = img + b * HWn;
  int ym = y > 0 ? y - 1 : 0, yp = y < 255 ? y + 1 : 255;
  int xm = x > 0 ? x - 1 : 0, xp = x < 255 ? x + 1 : 255;
  float a00 = p[ym * 256 + xm], a01 = p[ym * 256 + x], a02 = p[ym * 256 + xp];
  float a10 = p[y * 256 + xm], a12 = p[y * 256 + xp];
  float a20 = p[yp * 256 + xm], a21 = p[yp * 256 + x], a22 = p[yp * 256 + xp];
  float gx = (a02 - a00 + 2.f * (a12 - a10) + a22 - a20) * 0.125f;
  float gy = (a20 - a00 + 2.f * (a21 - a01) + a22 - a02) * 0.125f;
  gout[b * 131072 + y * 256 + x] = gx;
  gout[b * 131072 + 65536 + y * 256 + x] = gy;
}

__global__ void vblur_rg_kernel(const float* __restrict__ res_i, const float* __restrict__ g,
                                float* __restrict__ vtmp) {
  int idx = blockIdx.x * 256 + threadIdx.x;
  int b = idx >> 17;
  int c = (idx >> 16) & 1;
  int y = (idx >> 8) & 255;
  int x = idx & 255;
  float G[15]; make_gauss(G);
  const float* rb = res_i + b * HWn;
  const float* gb = g + b * 131072 + c * 65536;
  float s = 0.f;
#pragma unroll
  for (int t = 0; t < 15; t++) {
    int yy = y + t - 7;
    if ((unsigned)yy < 256u) {
      int o = yy * 256 + x;
      s += G[t] * (-rb[o] * gb[o]);
    }
  }
  vtmp[idx] = s;
}

__global__ void hblur_kernel(const float* __restrict__ vtmp, float* __restrict__ fields_i) {
  int idx = blockIdx.x * 256 + threadIdx.x;
  int b = idx >> 17;
  int c = (idx >> 16) & 1;
  int y = (idx >> 8) & 255;
  int x = idx & 255;
  float G[15]; make_gauss(G);
  const float* vb = vtmp + b * 131072 + c * 65536 + y * 256;
  float s = 0.f;
#pragma unroll
  for (int t = 0; t < 15; t++) {
    int xx = x + t - 7;
    if ((unsigned)xx < 256u) s += G[t] * vb[xx];
  }
  fields_i[((b * 65536) + (y * 256) + x) * 2 + c] = s;
}

// Fused conv1 (fp32 VALU -> hi/lo bf16 LDS) + conv2 (2-term split MFMA: exact
// activations x bf16 weights). Weights staged ONCE per tap (full 128-ic),
// VGPR-prefetched during the previous tap's MFMAs; 2 barriers per tap.
// Block: 16x8 pixel tile, 256 threads. LDS: x1h+x1l 95.6KB + whi 34KB = 129.6KB.
__global__ __launch_bounds__(256, 1) void conv12_kernel(
    const float* __restrict__ res_i, const float* __restrict__ img,
    const float* __restrict__ tgt, const float* __restrict__ w1,
    const ushort* __restrict__ w2h, ushort* __restrict__ x2p, int b0) {
  __shared__ ushort x1h[180 * 136];
  __shared__ ushort x1l[180 * 136];
  __shared__ ushort whi[128 * 136];
  const int tid = threadIdx.x;
  const int bb = blockIdx.z;
  const int b = b0 + bb;
  const int Y0 = blockIdx.y * 8, X0 = blockIdx.x * 16;
  const float* zb = res_i + b * HWn;
  const float* ib = img + b * HWn;
  const float* tb = tgt + b * HWn;

  // ---- Prefetch tap-0 weights into VGPRs (in flight during conv1 VALU) ----
  uint4 wreg[8];
#pragma unroll
  for (int i = 0; i < 8; i++) {
    int item = i * 256 + tid;          // 0..2047: 128 oc x 16 uint4-chunks
    int oc = item >> 4, c = item & 15;
    wreg[i] = *(const uint4*)(w2h + oc * 128 + c * 8);
  }

  // ---- Phase A: conv1 (3->100) + lrelu -> hi/lo bf16 in LDS ----
  // halo positions beyond the image MUST be zero (conv2 zero-pads x1).
  if (tid < 180) {
    int ly = tid / 18, lx = tid - ly * 18;
    int gy = Y0 + ly - 1, gx = X0 + lx - 1;
    const bool inb = (unsigned)gy < 256u && (unsigned)gx < 256u;
    float p[27];
#pragma unroll
    for (int dy = 0; dy < 3; dy++)
#pragma unroll
      for (int dx = 0; dx < 3; dx++) {
        int yy = gy + dy - 1, xx = gx + dx - 1;
        bool ok = (unsigned)yy < 256u && (unsigned)xx < 256u;
        int o = ok ? (yy * 256 + xx) : 0;
        int j = dy * 3 + dx;
        p[j] = ok ? zb[o] : 0.f;
        p[9 + j] = ok ? ib[o] : 0.f;
        p[18 + j] = ok ? tb[o] : 0.f;
      }
    const uint base = (uint)tid * 136u;
    for (int oc = 0; oc < 100; oc += 2) {
      const float* wa = w1 + oc * 27;
      float s0 = 0.f, s1 = 0.f;
#pragma unroll
      for (int j = 0; j < 27; j++) {
        s0 = fmaf(p[j], wa[j], s0);
        s1 = fmaf(p[j], wa[27 + j], s1);
      }
      s0 = inb ? lrelu(s0) : 0.f;
      s1 = inb ? lrelu(s1) : 0.f;
      ushort h0 = bf16r(s0), h1 = bf16r(s1);
      *(uint*)&x1h[base + oc] = (uint)h0 | ((uint)h1 << 16);
      *(uint*)&x1l[base + oc] =
          (uint)bf16r(s0 - bf2f(h0)) | ((uint)bf16r(s1 - bf2f(h1)) << 16);
    }
#pragma unroll
    for (int oc = 100; oc < 128; oc += 2) {
      *(uint*)&x1h[base + oc] = 0u;
      *(uint*)&x1l[base + oc] = 0u;
    }
  }

  // ---- stage tap-0 weights ----
#pragma unroll
  for (int i = 0; i < 8; i++) {
    int item = i * 256 + tid;
    int oc = item >> 4, c = item & 15;
    *(uint4*)&whi[oc * 136 + c * 8] = wreg[i];
  }
  __syncthreads();

  // ---- Phase B: conv2 via 2-term split MFMA ----
  const int lane = tid & 63, wv = tid >> 6;
  const int q = lane >> 4, n = lane & 15;
  f32x4 acc[2][7];
#pragma unroll
  for (int r = 0; r < 2; r++)
#pragma unroll
    for (int o = 0; o < 7; o++) acc[r][o] = (f32x4)(0.f);

  for (int tap = 0; tap < 9; tap++) {
    const int dy = tap / 3, dx = tap - dy * 3;
    if (tap < 8) {
      const ushort* wsrc = w2h + (tap + 1) * 16384;
#pragma unroll
      for (int i = 0; i < 8; i++) {
        int item = i * 256 + tid;
        int oc = item >> 4, c = item & 15;
        wreg[i] = *(const uint4*)(wsrc + oc * 128 + c * 8);
      }
    }
#pragma unroll
    for (int kc = 0; kc < 4; kc++) {
      const int ko = kc * 32 + q * 8;
      short8 ah[2], al[2];
#pragma unroll
      for (int r = 0; r < 2; r++) {
        uint off = (uint)((wv * 2 + r + dy) * 18 + n + dx) * 136u + ko;
        ah[r] = *(const short8*)&x1h[off];
        al[r] = *(const short8*)&x1l[off];
      }
#pragma unroll
      for (int o = 0; o < 7; o++) {
        short8 bv = *(const short8*)&whi[(uint)(o * 16 + n) * 136u + ko];
        acc[0][o] = __builtin_amdgcn_mfma_f32_16x16x32_bf16(ah[0], bv, acc[0][o], 0, 0, 0);
        acc[1][o] = __builtin_amdgcn_mfma_f32_16x16x32_bf16(ah[1], bv, acc[1][o], 0, 0, 0);
        acc[0][o] = __builtin_amdgcn_mfma_f32_16x16x32_bf16(al[0], bv, acc[0][o], 0, 0, 0);
        acc[1][o] = __builtin_amdgcn_mfma_f32_16x16x32_bf16(al[1], bv, acc[1][o], 0, 0, 0);
      }
    }
    __syncthreads();   // all waves done reading whi for this tap
    if (tap < 8) {
#pragma unroll
      for (int i = 0; i < 8; i++) {
        int item = i * 256 + tid;
        int oc = item >> 4, c = item & 15;
        *(uint4*)&whi[oc * 136 + c * 8] = wreg[i];
      }
      __syncthreads();
    }
  }

  // ---- Epilogue: lrelu -> bf16 planar x2p[oc][bb][y][x] (oc<100) ----
#pragma unroll
  for (int r = 0; r < 2; r++) {
    int y = Y0 + wv * 2 + r;
#pragma unroll
    for (int o = 0; o < 7; o++) {
      if (o == 6 && n >= 4) continue;   // oc>=100 unused
      int oc = o * 16 + n;
      uint lo = (uint)bf16r(lrelu(acc[r][o][0])) | ((uint)bf16r(lrelu(acc[r][o][1])) << 16);
      uint hi = (uint)bf16r(lrelu(acc[r][o][2])) | ((uint)bf16r(lrelu(acc[r][o][3])) << 16);
      uint2 v; v.x = lo; v.y = hi;
      *(uint2*)&x2p[(uint)oc * 131072u + (uint)bb * 65536u + (uint)y * 256u + X0 + q * 4] = v;
    }
  }
}

// conv3 (100->1) over planar bf16 x2p, fused residual update. 2 batches.
// Block = one image row (y uniform) -> coalesced x-reads per (oc,tap).
__global__ void conv3_kernel(const float* __restrict__ res_i,
                             const ushort* __restrict__ x2p,
                             const float* __restrict__ w3p2,
                             float* __restrict__ res_n, int b0) {
  int idx = blockIdx.x * 256 + threadIdx.x;   // 131072
  int bb = idx >> 16, y = (idx >> 8) & 255, x = idx & 255;
  int b = b0 + bb;
  float acc = 0.f;
  const ushort* base = x2p + bb * 65536 + y * 256 + x;
  for (int oc = 0; oc < 100; oc++) {
    const float* wt = w3p2 + oc * 9;
    const ushort* po = base + (uint)oc * 131072u;
#pragma unroll
    for (int tap = 0; tap < 9; tap++) {
      int dy = tap / 3, dx = tap - dy * 3;
      int yy = y + dy - 1, xx = x + dx - 1;
      if ((unsigned)yy < 256u && (unsigned)xx < 256u)
        acc = fmaf(bf2f(po[(dy - 1) * 256 + (dx - 1)]), wt[tap], acc);
    }
  }
  int o = (b << 16) + (idx & 65535);
  res_n[o] = res_i[o] - 0.2f * acc;
}

__global__ void phi_update_kernel(const float* __restrict__ fields_i,
                                  const float* __restrict__ phi_src,
                                  float* __restrict__ phi_dst, int step) {
  int idx = blockIdx.x * 256 + threadIdx.x;
  int k = idx >> 19;
  int r = idx & 524287;
  int b = r >> 16;
  int y = (r >> 8) & 255;
  int x = r & 255;
  float f0 = fields_i[2 * r], f1 = fields_i[2 * r + 1];
  float dx = (float)x - f0 * 0.2f;
  float dy = (float)y - f1 * 0.2f;
  float o0, o1;
  if (k == step) { o0 = dx; o1 = dy; }
  else bilin2(phi_src + (size_t)(k * 8 + b) * 131072, dx, dy, o0, o1);
  float* dst = phi_dst + (size_t)(k * 8 + b) * 131072 + (y * 256 + x) * 2;
  dst[0] = o0; dst[1] = o1;
}

__global__ void image_update_kernel(const float* __restrict__ source,
                                    const float* __restrict__ res_sec,
                                    const float* __restrict__ phi_cur, int step,
                                    float* __restrict__ img_out) {
  int idx = blockIdx.x * 256 + threadIdx.x;
  int b = idx >> 16;
  int y = (idx >> 8) & 255;
  int x = idx & 255;
  int pix2 = (y * 256 + x) * 2;
  const float* ph0 = phi_cur + (size_t)b * 131072 + pix2;
  float img = bilin1(source + b * HWn, ph0[0], ph0[1]);
  float rs = res_sec[(step + 1) * BHW + idx];
  for (int k = 1; k <= step; k++) {
    const float* ph = phi_cur + (size_t)(k * 8 + b) * 131072 + pix2;
    rs += bilin1(res_sec + k * BHW + b * HWn, ph[0], ph[1]);
  }
  img_out[idx] = img + rs * 8.0e-5f;
}

extern "C" void kernel_launch(void* const* d_in, const int* in_sizes, int n_in,
                              void* d_out, int out_size, void* d_ws, size_t ws_size,
                              hipStream_t stream) {
  const float* source = (const float*)d_in[0];
  const float* target = (const float*)d_in[1];
  const float* z0 = (const float*)d_in[3];
  const float* w1 = (const float*)d_in[4];
  const float* w2 = (const float*)d_in[5];
  const float* w3 = (const float*)d_in[6];
  float* out = (float*)d_out;
  float* ws = (float*)d_ws;

  float* ws_img = ws + WS_IMG;
  float* phiA = ws + WS_PHIA;
  float* phiB = ws + WS_PHIB;
  float* vtmp = ws + WS_VTMP;
  ushort* w2h = (ushort*)(ws + WS_W2H);
  float* w3p2 = ws + WS_W3P2;
  ushort* x2p = (ushort*)(ws + WS_X2P);

  hipMemcpyAsync(ws_img, source, BHW * sizeof(float), hipMemcpyDeviceToDevice, stream);
  init_res0_kernel<<<BHW / 256, 256, 0, stream>>>(z0, out + OUT_RES);
  w2p_prep<<<737280 / 256, 256, 0, stream>>>(w2, w2h);
  w3p2_prep<<<19, 256, 0, stream>>>(w3, w3p2);

  for (int i = 0; i < Lsteps; i++) {
    float* grads_i = out + OUT_GRADS + (size_t)i * 1048576;
    float* fields_i = out + OUT_FIELDS + (size_t)i * 1048576;
    const float* res_i = out + OUT_RES + (size_t)i * BHW;
    float* res_n = out + OUT_RES + (size_t)(i + 1) * BHW;
    float* phi_dst = (i % 2 == 0) ? phiA : phiB;
    float* phi_src = (i % 2 == 0) ? phiB : phiA;

    sobel_kernel<<<BHW / 256, 256, 0, stream>>>(ws_img, grads_i);
    vblur_rg_kernel<<<1048576 / 256, 256, 0, stream>>>(res_i, grads_i, vtmp);
    hblur_kernel<<<1048576 / 256, 256, 0, stream>>>(vtmp, fields_i);
    for (int b0 = 0; b0 < 8; b0 += 2) {
      conv12_kernel<<<dim3(16, 32, 2), 256, 0, stream>>>(
          res_i, ws_img, target, w1 + i * 2700, w2h + (size_t)i * 147456, x2p, b0);
      conv3_kernel<<<512, 256, 0, stream>>>(res_i, x2p, w3p2 + i * 900, res_n, b0);
    }
    phi_update_kernel<<<(i + 1) * (BHW / 256), 256, 0, stream>>>(fields_i, phi_src, phi_dst, i);
    image_update_kernel<<<BHW / 256, 256, 0, stream>>>(source, out + OUT_RES, phi_dst, i, ws_img);
  }
  hipMemcpyAsync(out + OUT_IMG, ws_img, BHW * sizeof(float), hipMemcpyDeviceToDevice, stream);
}

// Round 6
// 3674.326 us; speedup vs baseline: 1.9796x; 1.9796x over previous
//
#include <hip/hip_runtime.h>
#include <math.h>

typedef __attribute__((ext_vector_type(8))) short short8;
typedef __attribute__((ext_vector_type(4))) float f32x4;
typedef unsigned int uint;
typedef unsigned short ushort;

// Problem constants
#define Lsteps 5
#define Hn 256
#define Wn 256
#define HWn 65536           // 256*256
#define BHW 524288          // 8*65536

// d_out float offsets
#define OUT_IMG    0
#define OUT_FIELDS 524288
#define OUT_RES    5767168
#define OUT_GRADS  8912896

// workspace float offsets
#define WS_IMG   0           // 524288
#define WS_PHIA  524288      // 5242880  [5][8][256][256][2]
#define WS_PHIB  5767168     // 5242880
#define WS_VTMP  11010048    // 1048576  [8][2][256][256]
#define WS_W2H   12058624    // 368640 f (737280 ushort)  [5][9][128 oc][128 ic] bf16
#define WS_W3P   12427264    // 5760 f  [5][9 tap][128 ic] fp32
#define WS_X2    12433024    // 54525952 ushort = 27262976 f  [8][256][256][104] bf16

__device__ inline float lrelu(float s) { return s > 0.f ? s : 0.01f * s; }

__device__ inline ushort bf16r(float f) {
  uint u = __float_as_uint(f);
  return (ushort)((u + 0x7fffu + ((u >> 16) & 1u)) >> 16);
}
__device__ inline float bf2f(ushort h) { return __uint_as_float(((uint)h) << 16); }

__device__ inline void make_gauss(float* G) {
  float s = 0.f;
#pragma unroll
  for (int t = 0; t < 15; t++) {
    float d = (float)t - 7.f;
    G[t] = expf(-d * d * (1.f / 32.f));
    s += G[t];
  }
  float inv = 1.f / s;
#pragma unroll
  for (int t = 0; t < 15; t++) G[t] *= inv;
}

__device__ inline float bilin1(const float* __restrict__ p, float x, float y) {
  float x0f = floorf(x), y0f = floorf(y);
  int x0 = (int)x0f, y0 = (int)y0f;
  float fx = x - x0f, fy = y - y0f;
  float w00 = (1.f - fx) * (1.f - fy), w10 = fx * (1.f - fy);
  float w01 = (1.f - fx) * fy, w11 = fx * fy;
  float acc = 0.f;
  if ((unsigned)x0 < 256u && (unsigned)y0 < 256u) acc += w00 * p[y0 * 256 + x0];
  if ((unsigned)(x0 + 1) < 256u && (unsigned)y0 < 256u) acc += w10 * p[y0 * 256 + x0 + 1];
  if ((unsigned)x0 < 256u && (unsigned)(y0 + 1) < 256u) acc += w01 * p[(y0 + 1) * 256 + x0];
  if ((unsigned)(x0 + 1) < 256u && (unsigned)(y0 + 1) < 256u) acc += w11 * p[(y0 + 1) * 256 + x0 + 1];
  return acc;
}

__device__ inline void bilin2(const float* __restrict__ p, float x, float y,
                              float& o0, float& o1) {
  float x0f = floorf(x), y0f = floorf(y);
  int x0 = (int)x0f, y0 = (int)y0f;
  float fx = x - x0f, fy = y - y0f;
  float w00 = (1.f - fx) * (1.f - fy), w10 = fx * (1.f - fy);
  float w01 = (1.f - fx) * fy, w11 = fx * fy;
  o0 = 0.f; o1 = 0.f;
  if ((unsigned)x0 < 256u && (unsigned)y0 < 256u) {
    const float* q = p + (y0 * 256 + x0) * 2; o0 += w00 * q[0]; o1 += w00 * q[1];
  }
  if ((unsigned)(x0 + 1) < 256u && (unsigned)y0 < 256u) {
    const float* q = p + (y0 * 256 + x0 + 1) * 2; o0 += w10 * q[0]; o1 += w10 * q[1];
  }
  if ((unsigned)x0 < 256u && (unsigned)(y0 + 1) < 256u) {
    const float* q = p + ((y0 + 1) * 256 + x0) * 2; o0 += w01 * q[0]; o1 += w01 * q[1];
  }
  if ((unsigned)(x0 + 1) < 256u && (unsigned)(y0 + 1) < 256u) {
    const float* q = p + ((y0 + 1) * 256 + x0 + 1) * 2; o0 += w11 * q[0]; o1 += w11 * q[1];
  }
}

__global__ void init_res0_kernel(const float* __restrict__ z0, float* __restrict__ res0) {
  int idx = blockIdx.x * 256 + threadIdx.x;
  res0[idx] = z0[idx & 65535];
}

// w2 bf16: [l][tap][oc][ic], oc/ic zero-padded to 128
__global__ void w2p_prep(const float* __restrict__ w2, ushort* __restrict__ w2h) {
  int idx = blockIdx.x * 256 + threadIdx.x;     // 737280
  int l = idx / 147456;
  int r = idx - l * 147456;
  int tap = r >> 14;
  int r2 = r & 16383;
  int oc = r2 >> 7;
  int ic = r2 & 127;
  float v = (oc < 100 && ic < 100) ? w2[l * 90000 + oc * 900 + ic * 9 + tap] : 0.f;
  w2h[idx] = bf16r(v);
}

// w3p[l][tap][ic] fp32, ic zero-padded to 128
__global__ void w3p_prep(const float* __restrict__ w3, float* __restrict__ w3p) {
  int idx = blockIdx.x * 256 + threadIdx.x;     // 5760
  if (idx >= Lsteps * 9 * 128) return;
  int l = idx / 1152;
  int r = idx - l * 1152;
  int tap = r >> 7;
  int ic = r & 127;
  w3p[idx] = (ic < 100) ? w3[l * 900 + ic * 9 + tap] : 0.f;
}

__global__ void sobel_kernel(const float* __restrict__ img, float* __restrict__ gout) {
  int idx = blockIdx.x * 256 + threadIdx.x;
  int b = idx >> 16; int y = (idx >> 8) & 255; int x = idx & 255;
  const float* p = img + b * HWn;
  int ym = y > 0 ? y - 1 : 0, yp = y < 255 ? y + 1 : 255;
  int xm = x > 0 ? x - 1 : 0, xp = x < 255 ? x + 1 : 255;
  float a00 = p[ym * 256 + xm], a01 = p[ym * 256 + x], a02 = p[ym * 256 + xp];
  float a10 = p[y * 256 + xm], a12 = p[y * 256 + xp];
  float a20 = p[yp * 256 + xm], a21 = p[yp * 256 + x], a22 = p[yp * 256 + xp];
  float gx = (a02 - a00 + 2.f * (a12 - a10) + a22 - a20) * 0.125f;
  float gy = (a20 - a00 + 2.f * (a21 - a01) + a22 - a02) * 0.125f;
  gout[b * 131072 + y * 256 + x] = gx;
  gout[b * 131072 + 65536 + y * 256 + x] = gy;
}

__global__ void vblur_rg_kernel(const float* __restrict__ res_i, const float* __restrict__ g,
                                float* __restrict__ vtmp) {
  int idx = blockIdx.x * 256 + threadIdx.x;
  int b = idx >> 17;
  int c = (idx >> 16) & 1;
  int y = (idx >> 8) & 255;
  int x = idx & 255;
  float G[15]; make_gauss(G);
  const float* rb = res_i + b * HWn;
  const float* gb = g + b * 131072 + c * 65536;
  float s = 0.f;
#pragma unroll
  for (int t = 0; t < 15; t++) {
    int yy = y + t - 7;
    if ((unsigned)yy < 256u) {
      int o = yy * 256 + x;
      s += G[t] * (-rb[o] * gb[o]);
    }
  }
  vtmp[idx] = s;
}

__global__ void hblur_kernel(const float* __restrict__ vtmp, float* __restrict__ fields_i) {
  int idx = blockIdx.x * 256 + threadIdx.x;
  int b = idx >> 17;
  int c = (idx >> 16) & 1;
  int y = (idx >> 8) & 255;
  int x = idx & 255;
  float G[15]; make_gauss(G);
  const float* vb = vtmp + b * 131072 + c * 65536 + y * 256;
  float s = 0.f;
#pragma unroll
  for (int t = 0; t < 15; t++) {
    int xx = x + t - 7;
    if ((unsigned)xx < 256u) s += G[t] * vb[xx];
  }
  fields_i[((b * 65536) + (y * 256) + x) * 2 + c] = s;
}

// Fused conv1 (fp32 VALU -> bf16 LDS) + conv2 (bf16 MFMA, B-fragments read
// directly from global/L1/L2 — no weight LDS, no per-tap barriers).
// Block: 16x8 pixel tile, 256 threads, LDS 48KB -> 3 blocks/CU (12 waves).
__global__ __launch_bounds__(256, 3) void conv12_kernel(
    const float* __restrict__ res_i, const float* __restrict__ img,
    const float* __restrict__ tgt, const float* __restrict__ w1,
    const ushort* __restrict__ w2h, ushort* __restrict__ x2) {
  __shared__ ushort x1s[180 * 136];
  const int tid = threadIdx.x;
  const int b = blockIdx.z;
  const int Y0 = blockIdx.y * 8, X0 = blockIdx.x * 16;
  const float* zb = res_i + b * HWn;
  const float* ib = img + b * HWn;
  const float* tb = tgt + b * HWn;

  // ---- Phase A: conv1 (3->100) + lrelu -> bf16 LDS ----
  // halo positions beyond the image MUST be zero (conv2 zero-pads x1).
  if (tid < 180) {
    int ly = tid / 18, lx = tid - ly * 18;
    int gy = Y0 + ly - 1, gx = X0 + lx - 1;
    const bool inb = (unsigned)gy < 256u && (unsigned)gx < 256u;
    float p[27];
#pragma unroll
    for (int dy = 0; dy < 3; dy++)
#pragma unroll
      for (int dx = 0; dx < 3; dx++) {
        int yy = gy + dy - 1, xx = gx + dx - 1;
        bool ok = (unsigned)yy < 256u && (unsigned)xx < 256u;
        int o = ok ? (yy * 256 + xx) : 0;
        int j = dy * 3 + dx;
        p[j] = ok ? zb[o] : 0.f;
        p[9 + j] = ok ? ib[o] : 0.f;
        p[18 + j] = ok ? tb[o] : 0.f;
      }
    const uint base = (uint)tid * 136u;
    for (int oc = 0; oc < 100; oc += 2) {
      const float* wa = w1 + oc * 27;
      float s0 = 0.f, s1 = 0.f;
#pragma unroll
      for (int j = 0; j < 27; j++) {
        s0 = fmaf(p[j], wa[j], s0);
        s1 = fmaf(p[j], wa[27 + j], s1);
      }
      s0 = inb ? lrelu(s0) : 0.f;
      s1 = inb ? lrelu(s1) : 0.f;
      *(uint*)&x1s[base + oc] = (uint)bf16r(s0) | ((uint)bf16r(s1) << 16);
    }
#pragma unroll
    for (int oc = 100; oc < 128; oc += 2) *(uint*)&x1s[base + oc] = 0u;
  }
  __syncthreads();

  // ---- Phase B: conv2 via bf16 MFMA; B streamed from global (L1/L2 shared) ----
  const int lane = tid & 63, wv = tid >> 6;
  const int q = lane >> 4, n = lane & 15;
  f32x4 acc[2][7];
#pragma unroll
  for (int r = 0; r < 2; r++)
#pragma unroll
    for (int o = 0; o < 7; o++) acc[r][o] = (f32x4)(0.f);

  for (int tap = 0; tap < 9; tap++) {
    const int dy = tap / 3, dx = tap - dy * 3;
    const ushort* wt = w2h + tap * 16384 + n * 128 + q * 8;
#pragma unroll
    for (int kc = 0; kc < 4; kc++) {
      const int ko = kc * 32 + q * 8;
      short8 a0 = *(const short8*)&x1s[(uint)((wv * 2 + dy) * 18 + n + dx) * 136u + ko];
      short8 a1 = *(const short8*)&x1s[(uint)((wv * 2 + 1 + dy) * 18 + n + dx) * 136u + ko];
      const ushort* wk = wt + kc * 32;
#pragma unroll
      for (int o = 0; o < 7; o++) {
        short8 bv = *(const short8*)(wk + o * 2048);   // oc = o*16+n, ic = ko..ko+7
        acc[0][o] = __builtin_amdgcn_mfma_f32_16x16x32_bf16(a0, bv, acc[0][o], 0, 0, 0);
        acc[1][o] = __builtin_amdgcn_mfma_f32_16x16x32_bf16(a1, bv, acc[1][o], 0, 0, 0);
      }
    }
  }

  // ---- Epilogue: lrelu -> bf16 channels-last x2[b][y][x][104] ----
#pragma unroll
  for (int r = 0; r < 2; r++) {
    int y = Y0 + wv * 2 + r;
#pragma unroll
    for (int o = 0; o < 7; o++) {
      if (o == 6 && n >= 8) continue;       // oc >= 104: no storage
      int oc = o * 16 + n;
      bool pad = (oc >= 100);               // channels 100..103: write zeros
#pragma unroll
      for (int v = 0; v < 4; v++) {
        int x = X0 + q * 4 + v;
        ushort val = pad ? (ushort)0 : bf16r(lrelu(acc[r][o][v]));
        x2[(size_t)((b << 16) + y * 256 + x) * 104 + oc] = val;
      }
    }
  }
}

// conv3 (100->1) over channels-last bf16 x2, fused residual update. All 8 batches.
__global__ void conv3_kernel(const float* __restrict__ res_i,
                             const ushort* __restrict__ x2,
                             const float* __restrict__ w3p,
                             float* __restrict__ res_n) {
  int idx = blockIdx.x * 256 + threadIdx.x;   // 524288
  int b = idx >> 16, y = (idx >> 8) & 255, x = idx & 255;
  float acc = 0.f;
#pragma unroll
  for (int tap = 0; tap < 9; tap++) {
    int dy = tap / 3, dx = tap - dy * 3;
    int yy = y + dy - 1, xx = x + dx - 1;
    if ((unsigned)yy < 256u && (unsigned)xx < 256u) {
      const ushort* px = x2 + (size_t)((b << 16) + yy * 256 + xx) * 104;
      const float* wt = w3p + tap * 128;
#pragma unroll
      for (int c = 0; c < 13; c++) {   // 104 channels; 100..103 stored as zero
        uint4 u = *(const uint4*)(px + c * 8);
        const float* w8 = wt + c * 8;
        acc = fmaf(__uint_as_float(u.x << 16), w8[0], acc);
        acc = fmaf(__uint_as_float(u.x & 0xffff0000u), w8[1], acc);
        acc = fmaf(__uint_as_float(u.y << 16), w8[2], acc);
        acc = fmaf(__uint_as_float(u.y & 0xffff0000u), w8[3], acc);
        acc = fmaf(__uint_as_float(u.z << 16), w8[4], acc);
        acc = fmaf(__uint_as_float(u.z & 0xffff0000u), w8[5], acc);
        acc = fmaf(__uint_as_float(u.w << 16), w8[6], acc);
        acc = fmaf(__uint_as_float(u.w & 0xffff0000u), w8[7], acc);
      }
    }
  }
  res_n[idx] = res_i[idx] - 0.2f * acc;
}

__global__ void phi_update_kernel(const float* __restrict__ fields_i,
                                  const float* __restrict__ phi_src,
                                  float* __restrict__ phi_dst, int step) {
  int idx = blockIdx.x * 256 + threadIdx.x;
  int k = idx >> 19;
  int r = idx & 524287;
  int b = r >> 16;
  int y = (r >> 8) & 255;
  int x = r & 255;
  float f0 = fields_i[2 * r], f1 = fields_i[2 * r + 1];
  float dx = (float)x - f0 * 0.2f;
  float dy = (float)y - f1 * 0.2f;
  float o0, o1;
  if (k == step) { o0 = dx; o1 = dy; }
  else bilin2(phi_src + (size_t)(k * 8 + b) * 131072, dx, dy, o0, o1);
  float* dst = phi_dst + (size_t)(k * 8 + b) * 131072 + (y * 256 + x) * 2;
  dst[0] = o0; dst[1] = o1;
}

__global__ void image_update_kernel(const float* __restrict__ source,
                                    const float* __restrict__ res_sec,
                                    const float* __restrict__ phi_cur, int step,
                                    float* __restrict__ img_out) {
  int idx = blockIdx.x * 256 + threadIdx.x;
  int b = idx >> 16;
  int y = (idx >> 8) & 255;
  int x = idx & 255;
  int pix2 = (y * 256 + x) * 2;
  const float* ph0 = phi_cur + (size_t)b * 131072 + pix2;
  float img = bilin1(source + b * HWn, ph0[0], ph0[1]);
  float rs = res_sec[(step + 1) * BHW + idx];
  for (int k = 1; k <= step; k++) {
    const float* ph = phi_cur + (size_t)(k * 8 + b) * 131072 + pix2;
    rs += bilin1(res_sec + k * BHW + b * HWn, ph[0], ph[1]);
  }
  img_out[idx] = img + rs * 8.0e-5f;
}

extern "C" void kernel_launch(void* const* d_in, const int* in_sizes, int n_in,
                              void* d_out, int out_size, void* d_ws, size_t ws_size,
                              hipStream_t stream) {
  const float* source = (const float*)d_in[0];
  const float* target = (const float*)d_in[1];
  const float* z0 = (const float*)d_in[3];
  const float* w1 = (const float*)d_in[4];
  const float* w2 = (const float*)d_in[5];
  const float* w3 = (const float*)d_in[6];
  float* out = (float*)d_out;
  float* ws = (float*)d_ws;

  float* ws_img = ws + WS_IMG;
  float* phiA = ws + WS_PHIA;
  float* phiB = ws + WS_PHIB;
  float* vtmp = ws + WS_VTMP;
  ushort* w2h = (ushort*)(ws + WS_W2H);
  float* w3p = ws + WS_W3P;
  ushort* x2 = (ushort*)(ws + WS_X2);

  hipMemcpyAsync(ws_img, source, BHW * sizeof(float), hipMemcpyDeviceToDevice, stream);
  init_res0_kernel<<<BHW / 256, 256, 0, stream>>>(z0, out + OUT_RES);
  w2p_prep<<<737280 / 256, 256, 0, stream>>>(w2, w2h);
  w3p_prep<<<23, 256, 0, stream>>>(w3, w3p);

  for (int i = 0; i < Lsteps; i++) {
    float* grads_i = out + OUT_GRADS + (size_t)i * 1048576;
    float* fields_i = out + OUT_FIELDS + (size_t)i * 1048576;
    const float* res_i = out + OUT_RES + (size_t)i * BHW;
    float* res_n = out + OUT_RES + (size_t)(i + 1) * BHW;
    float* phi_dst = (i % 2 == 0) ? phiA : phiB;
    float* phi_src = (i % 2 == 0) ? phiB : phiA;

    sobel_kernel<<<BHW / 256, 256, 0, stream>>>(ws_img, grads_i);
    vblur_rg_kernel<<<1048576 / 256, 256, 0, stream>>>(res_i, grads_i, vtmp);
    hblur_kernel<<<1048576 / 256, 256, 0, stream>>>(vtmp, fields_i);
    conv12_kernel<<<dim3(16, 32, 8), 256, 0, stream>>>(
        res_i, ws_img, target, w1 + i * 2700, w2h + (size_t)i * 147456, x2);
    conv3_kernel<<<BHW / 256, 256, 0, stream>>>(res_i, x2, w3p + i * 1152, res_n);
    phi_update_kernel<<<(i + 1) * (BHW / 256), 256, 0, stream>>>(fields_i, phi_src, phi_dst, i);
    image_update_kernel<<<BHW / 256, 256, 0, stream>>>(source, out + OUT_RES, phi_dst, i, ws_img);
  }
  hipMemcpyAsync(out + OUT_IMG, ws_img, BHW * sizeof(float), hipMemcpyDeviceToDevice, stream);
}

// Round 8
// 2667.900 us; speedup vs baseline: 2.7263x; 1.3772x over previous
//
#include <hip/hip_runtime.h>
#include <math.h>

typedef __attribute__((ext_vector_type(8))) short short8;
typedef __attribute__((ext_vector_type(4))) float f32x4;
typedef unsigned int uint;
typedef unsigned short ushort;

// Problem constants
#define Lsteps 5
#define Hn 256
#define Wn 256
#define HWn 65536           // 256*256
#define BHW 524288          // 8*65536

// d_out float offsets
#define OUT_IMG    0
#define OUT_FIELDS 524288
#define OUT_RES    5767168
#define OUT_GRADS  8912896

// workspace float offsets
#define WS_IMG   0           // 524288
#define WS_PHIA  524288      // 5242880  [5][8][256][256][2]
#define WS_PHIB  5767168     // 5242880
#define WS_VTMP  11010048    // 1048576  [8][2][256][256]
#define WS_W2B   12058624    // 322560 f = 645120 ushort  [5][9 tap][4 kc][7 o][64 lane][8] bf16
#define WS_W3P   12381184    // 5760 f  [5][9 tap][128 ic] fp32
#define WS_X2    12386944    // 27262976 f = 54525952 ushort  [8][256][256][104] bf16

__device__ inline float lrelu(float s) { return s > 0.f ? s : 0.01f * s; }

__device__ inline ushort bf16r(float f) {
  uint u = __float_as_uint(f);
  return (ushort)((u + 0x7fffu + ((u >> 16) & 1u)) >> 16);
}

__device__ inline void make_gauss(float* G) {
  float s = 0.f;
#pragma unroll
  for (int t = 0; t < 15; t++) {
    float d = (float)t - 7.f;
    G[t] = expf(-d * d * (1.f / 32.f));
    s += G[t];
  }
  float inv = 1.f / s;
#pragma unroll
  for (int t = 0; t < 15; t++) G[t] *= inv;
}

__device__ inline float bilin1(const float* __restrict__ p, float x, float y) {
  float x0f = floorf(x), y0f = floorf(y);
  int x0 = (int)x0f, y0 = (int)y0f;
  float fx = x - x0f, fy = y - y0f;
  float w00 = (1.f - fx) * (1.f - fy), w10 = fx * (1.f - fy);
  float w01 = (1.f - fx) * fy, w11 = fx * fy;
  float acc = 0.f;
  if ((unsigned)x0 < 256u && (unsigned)y0 < 256u) acc += w00 * p[y0 * 256 + x0];
  if ((unsigned)(x0 + 1) < 256u && (unsigned)y0 < 256u) acc += w10 * p[y0 * 256 + x0 + 1];
  if ((unsigned)x0 < 256u && (unsigned)(y0 + 1) < 256u) acc += w01 * p[(y0 + 1) * 256 + x0];
  if ((unsigned)(x0 + 1) < 256u && (unsigned)(y0 + 1) < 256u) acc += w11 * p[(y0 + 1) * 256 + x0 + 1];
  return acc;
}

__device__ inline void bilin2(const float* __restrict__ p, float x, float y,
                              float& o0, float& o1) {
  float x0f = floorf(x), y0f = floorf(y);
  int x0 = (int)x0f, y0 = (int)y0f;
  float fx = x - x0f, fy = y - y0f;
  float w00 = (1.f - fx) * (1.f - fy), w10 = fx * (1.f - fy);
  float w01 = (1.f - fx) * fy, w11 = fx * fy;
  o0 = 0.f; o1 = 0.f;
  if ((unsigned)x0 < 256u && (unsigned)y0 < 256u) {
    const float* q = p + (y0 * 256 + x0) * 2; o0 += w00 * q[0]; o1 += w00 * q[1];
  }
  if ((unsigned)(x0 + 1) < 256u && (unsigned)y0 < 256u) {
    const float* q = p + (y0 * 256 + x0 + 1) * 2; o0 += w10 * q[0]; o1 += w10 * q[1];
  }
  if ((unsigned)x0 < 256u && (unsigned)(y0 + 1) < 256u) {
    const float* q = p + ((y0 + 1) * 256 + x0) * 2; o0 += w01 * q[0]; o1 += w01 * q[1];
  }
  if ((unsigned)(x0 + 1) < 256u && (unsigned)(y0 + 1) < 256u) {
    const float* q = p + ((y0 + 1) * 256 + x0 + 1) * 2; o0 += w11 * q[0]; o1 += w11 * q[1];
  }
}

__global__ void init_res0_kernel(const float* __restrict__ z0, float* __restrict__ res0) {
  int idx = blockIdx.x * 256 + threadIdx.x;
  res0[idx] = z0[idx & 65535];
}

// Fragment-ordered bf16 weights: [l][tap][kc][o][lane][8], lane=q*16+n,
// element j (0..7): oc = o*16+n, ic = kc*32+q*8+j. oc/ic>=100 zero-padded.
// Strides (ushorts): tap=14336, kc=3584, o=512, lane=8, j=1.
__global__ void w2b_prep(const float* __restrict__ w2, ushort* __restrict__ w2b) {
  int idx = blockIdx.x * 256 + threadIdx.x;     // 645120
  if (idx >= Lsteps * 129024) return;
  int l = idx / 129024;
  int r = idx - l * 129024;
  int tap = r / 14336;
  int r2 = r - tap * 14336;
  int kc = r2 / 3584;
  int r3 = r2 - kc * 3584;
  int o = r3 >> 9;
  int r4 = r3 & 511;
  int lane = r4 >> 3;
  int j = r4 & 7;
  int q = lane >> 4, n = lane & 15;
  int oc = o * 16 + n;
  int ic = kc * 32 + q * 8 + j;
  float v = (oc < 100 && ic < 100) ? w2[l * 90000 + oc * 900 + ic * 9 + tap] : 0.f;
  w2b[idx] = bf16r(v);
}

// w3p[l][tap][ic] fp32, ic zero-padded to 128
__global__ void w3p_prep(const float* __restrict__ w3, float* __restrict__ w3p) {
  int idx = blockIdx.x * 256 + threadIdx.x;     // 5760
  if (idx >= Lsteps * 9 * 128) return;
  int l = idx / 1152;
  int r = idx - l * 1152;
  int tap = r >> 7;
  int ic = r & 127;
  w3p[idx] = (ic < 100) ? w3[l * 900 + ic * 9 + tap] : 0.f;
}

__global__ void sobel_kernel(const float* __restrict__ img, float* __restrict__ gout) {
  int idx = blockIdx.x * 256 + threadIdx.x;
  int b = idx >> 16; int y = (idx >> 8) & 255; int x = idx & 255;
  const float* p = img + b * HWn;
  int ym = y > 0 ? y - 1 : 0, yp = y < 255 ? y + 1 : 255;
  int xm = x > 0 ? x - 1 : 0, xp = x < 255 ? x + 1 : 255;
  float a00 = p[ym * 256 + xm], a01 = p[ym * 256 + x], a02 = p[ym * 256 + xp];
  float a10 = p[y * 256 + xm], a12 = p[y * 256 + xp];
  float a20 = p[yp * 256 + xm], a21 = p[yp * 256 + x], a22 = p[yp * 256 + xp];
  float gx = (a02 - a00 + 2.f * (a12 - a10) + a22 - a20) * 0.125f;
  float gy = (a20 - a00 + 2.f * (a21 - a01) + a22 - a02) * 0.125f;
  gout[b * 131072 + y * 256 + x] = gx;
  gout[b * 131072 + 65536 + y * 256 + x] = gy;
}

__global__ void vblur_rg_kernel(const float* __restrict__ res_i, const float* __restrict__ g,
                                float* __restrict__ vtmp) {
  int idx = blockIdx.x * 256 + threadIdx.x;
  int b = idx >> 17;
  int c = (idx >> 16) & 1;
  int y = (idx >> 8) & 255;
  int x = idx & 255;
  float G[15]; make_gauss(G);
  const float* rb = res_i + b * HWn;
  const float* gb = g + b * 131072 + c * 65536;
  float s = 0.f;
#pragma unroll
  for (int t = 0; t < 15; t++) {
    int yy = y + t - 7;
    if ((unsigned)yy < 256u) {
      int o = yy * 256 + x;
      s += G[t] * (-rb[o] * gb[o]);
    }
  }
  vtmp[idx] = s;
}

__global__ void hblur_kernel(const float* __restrict__ vtmp, float* __restrict__ fields_i) {
  int idx = blockIdx.x * 256 + threadIdx.x;
  int b = idx >> 17;
  int c = (idx >> 16) & 1;
  int y = (idx >> 8) & 255;
  int x = idx & 255;
  float G[15]; make_gauss(G);
  const float* vb = vtmp + b * 131072 + c * 65536 + y * 256;
  float s = 0.f;
#pragma unroll
  for (int t = 0; t < 15; t++) {
    int xx = x + t - 7;
    if ((unsigned)xx < 256u) s += G[t] * vb[xx];
  }
  fields_i[((b * 65536) + (y * 256) + x) * 2 + c] = s;
}

// Fused conv1 (fp32 VALU -> bf16 LDS) + conv2 (bf16 MFMA).
// B-fragments: fragment-ordered global layout, loaded in 14-wide batches
// (coalesced lane*16B) -> one vmcnt drain per 28 MFMAs.
// Block: 16x8 pixel tile, 256 threads, LDS 48KB, 3 blocks/CU.
__global__ __launch_bounds__(256, 3) void conv12_kernel(
    const float* __restrict__ res_i, const float* __restrict__ img,
    const float* __restrict__ tgt, const float* __restrict__ w1,
    const short8* __restrict__ w2b, ushort* __restrict__ x2) {
  __shared__ ushort x1s[180 * 136];
  const int tid = threadIdx.x;
  const int b = blockIdx.z;
  const int Y0 = blockIdx.y * 8, X0 = blockIdx.x * 16;
  const float* zb = res_i + b * HWn;
  const float* ib = img + b * HWn;
  const float* tb = tgt + b * HWn;

  // ---- Phase A: conv1 (3->100) + lrelu -> bf16 LDS ----
  // halo positions beyond the image MUST be zero (conv2 zero-pads x1).
  if (tid < 180) {
    int ly = tid / 18, lx = tid - ly * 18;
    int gy = Y0 + ly - 1, gx = X0 + lx - 1;
    const bool inb = (unsigned)gy < 256u && (unsigned)gx < 256u;
    float p[27];
#pragma unroll
    for (int dy = 0; dy < 3; dy++)
#pragma unroll
      for (int dx = 0; dx < 3; dx++) {
        int yy = gy + dy - 1, xx = gx + dx - 1;
        bool ok = (unsigned)yy < 256u && (unsigned)xx < 256u;
        int o = ok ? (yy * 256 + xx) : 0;
        int j = dy * 3 + dx;
        p[j] = ok ? zb[o] : 0.f;
        p[9 + j] = ok ? ib[o] : 0.f;
        p[18 + j] = ok ? tb[o] : 0.f;
      }
    const uint base = (uint)tid * 136u;
    for (int oc = 0; oc < 100; oc += 2) {
      const float* wa = w1 + oc * 27;
      float s0 = 0.f, s1 = 0.f;
#pragma unroll
      for (int j = 0; j < 27; j++) {
        s0 = fmaf(p[j], wa[j], s0);
        s1 = fmaf(p[j], wa[27 + j], s1);
      }
      s0 = inb ? lrelu(s0) : 0.f;
      s1 = inb ? lrelu(s1) : 0.f;
      *(uint*)&x1s[base + oc] = (uint)bf16r(s0) | ((uint)bf16r(s1) << 16);
    }
#pragma unroll
    for (int oc = 100; oc < 128; oc += 2) *(uint*)&x1s[base + oc] = 0u;
  }
  __syncthreads();

  // ---- Phase B: conv2 via bf16 MFMA, half-tap batched B loads ----
  const int lane = tid & 63, wv = tid >> 6;
  const int q = lane >> 4, n = lane & 15;
  f32x4 acc[2][7];
#pragma unroll
  for (int r = 0; r < 2; r++)
#pragma unroll
    for (int o = 0; o < 7; o++) acc[r][o] = (f32x4)(0.f);

  for (int tap = 0; tap < 9; tap++) {
    const int dy = tap / 3, dx = tap - dy * 3;
    const uint arow0 = (uint)((wv * 2 + dy) * 18 + n + dx) * 136u;
    const uint arow1 = arow0 + 136u * 18u;   // row +1
#pragma unroll
    for (int half = 0; half < 2; half++) {
      // 14 coalesced fragment loads (kc = half*2, half*2+1; o = 0..6)
      const short8* src = w2b + (uint)(tap * 4 + half * 2) * 448u + lane;
      short8 wbuf[14];
#pragma unroll
      for (int u = 0; u < 14; u++) wbuf[u] = src[(uint)u * 64u];
#pragma unroll
      for (int kr = 0; kr < 2; kr++) {
        const int ko = (half * 2 + kr) * 32 + q * 8;
        short8 a0 = *(const short8*)&x1s[arow0 + ko];
        short8 a1 = *(const short8*)&x1s[arow1 + ko];
#pragma unroll
        for (int o = 0; o < 7; o++) {
          acc[0][o] = __builtin_amdgcn_mfma_f32_16x16x32_bf16(a0, wbuf[kr * 7 + o], acc[0][o], 0, 0, 0);
          acc[1][o] = __builtin_amdgcn_mfma_f32_16x16x32_bf16(a1, wbuf[kr * 7 + o], acc[1][o], 0, 0, 0);
        }
      }
    }
  }

  // ---- Epilogue: lrelu -> bf16 channels-last x2[b][y][x][104] ----
#pragma unroll
  for (int r = 0; r < 2; r++) {
    int y = Y0 + wv * 2 + r;
#pragma unroll
    for (int o = 0; o < 7; o++) {
      if (o == 6 && n >= 8) continue;       // oc >= 104: no storage
      int oc = o * 16 + n;
      bool pad = (oc >= 100);               // channels 100..103: write zeros
#pragma unroll
      for (int v = 0; v < 4; v++) {
        int x = X0 + q * 4 + v;
        ushort val = pad ? (ushort)0 : bf16r(lrelu(acc[r][o][v]));
        x2[(size_t)((b << 16) + y * 256 + x) * 104 + oc] = val;
      }
    }
  }
}

// conv3 (100->1) over channels-last bf16 x2, fused residual update. All 8 batches.
__global__ void conv3_kernel(const float* __restrict__ res_i,
                             const ushort* __restrict__ x2,
                             const float* __restrict__ w3p,
                             float* __restrict__ res_n) {
  int idx = blockIdx.x * 256 + threadIdx.x;   // 524288
  int b = idx >> 16, y = (idx >> 8) & 255, x = idx & 255;
  float acc = 0.f;
#pragma unroll
  for (int tap = 0; tap < 9; tap++) {
    int dy = tap / 3, dx = tap - dy * 3;
    int yy = y + dy - 1, xx = x + dx - 1;
    if ((unsigned)yy < 256u && (unsigned)xx < 256u) {
      const ushort* px = x2 + (size_t)((b << 16) + yy * 256 + xx) * 104;
      const float* wt = w3p + tap * 128;
#pragma unroll
      for (int c = 0; c < 13; c++) {   // 104 channels; 100..103 stored as zero
        uint4 u = *(const uint4*)(px + c * 8);
        const float* w8 = wt + c * 8;
        acc = fmaf(__uint_as_float(u.x << 16), w8[0], acc);
        acc = fmaf(__uint_as_float(u.x & 0xffff0000u), w8[1], acc);
        acc = fmaf(__uint_as_float(u.y << 16), w8[2], acc);
        acc = fmaf(__uint_as_float(u.y & 0xffff0000u), w8[3], acc);
        acc = fmaf(__uint_as_float(u.z << 16), w8[4], acc);
        acc = fmaf(__uint_as_float(u.z & 0xffff0000u), w8[5], acc);
        acc = fmaf(__uint_as_float(u.w << 16), w8[6], acc);
        acc = fmaf(__uint_as_float(u.w & 0xffff0000u), w8[7], acc);
      }
    }
  }
  res_n[idx] = res_i[idx] - 0.2f * acc;
}

__global__ void phi_update_kernel(const float* __restrict__ fields_i,
                                  const float* __restrict__ phi_src,
                                  float* __restrict__ phi_dst, int step) {
  int idx = blockIdx.x * 256 + threadIdx.x;
  int k = idx >> 19;
  int r = idx & 524287;
  int b = r >> 16;
  int y = (r >> 8) & 255;
  int x = r & 255;
  float f0 = fields_i[2 * r], f1 = fields_i[2 * r + 1];
  float dx = (float)x - f0 * 0.2f;
  float dy = (float)y - f1 * 0.2f;
  float o0, o1;
  if (k == step) { o0 = dx; o1 = dy; }
  else bilin2(phi_src + (size_t)(k * 8 + b) * 131072, dx, dy, o0, o1);
  float* dst = phi_dst + (size_t)(k * 8 + b) * 131072 + (y * 256 + x) * 2;
  dst[0] = o0; dst[1] = o1;
}

__global__ void image_update_kernel(const float* __restrict__ source,
                                    const float* __restrict__ res_sec,
                                    const float* __restrict__ phi_cur, int step,
                                    float* __restrict__ img_out) {
  int idx = blockIdx.x * 256 + threadIdx.x;
  int b = idx >> 16;
  int y = (idx >> 8) & 255;
  int x = idx & 255;
  int pix2 = (y * 256 + x) * 2;
  const float* ph0 = phi_cur + (size_t)b * 131072 + pix2;
  float img = bilin1(source + b * HWn, ph0[0], ph0[1]);
  float rs = res_sec[(step + 1) * BHW + idx];
  for (int k = 1; k <= step; k++) {
    const float* ph = phi_cur + (size_t)(k * 8 + b) * 131072 + pix2;
    rs += bilin1(res_sec + k * BHW + b * HWn, ph[0], ph[1]);
  }
  img_out[idx] = img + rs * 8.0e-5f;
}

extern "C" void kernel_launch(void* const* d_in, const int* in_sizes, int n_in,
                              void* d_out, int out_size, void* d_ws, size_t ws_size,
                              hipStream_t stream) {
  const float* source = (const float*)d_in[0];
  const float* target = (const float*)d_in[1];
  const float* z0 = (const float*)d_in[3];
  const float* w1 = (const float*)d_in[4];
  const float* w2 = (const float*)d_in[5];
  const float* w3 = (const float*)d_in[6];
  float* out = (float*)d_out;
  float* ws = (float*)d_ws;

  float* ws_img = ws + WS_IMG;
  float* phiA = ws + WS_PHIA;
  float* phiB = ws + WS_PHIB;
  float* vtmp = ws + WS_VTMP;
  ushort* w2b = (ushort*)(ws + WS_W2B);
  float* w3p = ws + WS_W3P;
  ushort* x2 = (ushort*)(ws + WS_X2);

  hipMemcpyAsync(ws_img, source, BHW * sizeof(float), hipMemcpyDeviceToDevice, stream);
  init_res0_kernel<<<BHW / 256, 256, 0, stream>>>(z0, out + OUT_RES);
  w2b_prep<<<(Lsteps * 129024 + 255) / 256, 256, 0, stream>>>(w2, w2b);
  w3p_prep<<<23, 256, 0, stream>>>(w3, w3p);

  for (int i = 0; i < Lsteps; i++) {
    float* grads_i = out + OUT_GRADS + (size_t)i * 1048576;
    float* fields_i = out + OUT_FIELDS + (size_t)i * 1048576;
    const float* res_i = out + OUT_RES + (size_t)i * BHW;
    float* res_n = out + OUT_RES + (size_t)(i + 1) * BHW;
    float* phi_dst = (i % 2 == 0) ? phiA : phiB;
    float* phi_src = (i % 2 == 0) ? phiB : phiA;

    sobel_kernel<<<BHW / 256, 256, 0, stream>>>(ws_img, grads_i);
    vblur_rg_kernel<<<1048576 / 256, 256, 0, stream>>>(res_i, grads_i, vtmp);
    hblur_kernel<<<1048576 / 256, 256, 0, stream>>>(vtmp, fields_i);
    conv12_kernel<<<dim3(16, 32, 8), 256, 0, stream>>>(
        res_i, ws_img, target, w1 + i * 2700,
        (const short8*)(w2b + (size_t)i * 129024), x2);
    conv3_kernel<<<BHW / 256, 256, 0, stream>>>(res_i, x2, w3p + i * 1152, res_n);
    phi_update_kernel<<<(i + 1) * (BHW / 256), 256, 0, stream>>>(fields_i, phi_src, phi_dst, i);
    image_update_kernel<<<BHW / 256, 256, 0, stream>>>(source, out + OUT_RES, phi_dst, i, ws_img);
  }
  hipMemcpyAsync(out + OUT_IMG, ws_img, BHW * sizeof(float), hipMemcpyDeviceToDevice, stream);
}